// Round 1
// baseline (3462.247 us; speedup 1.0000x reference)
//
#include <hip/hip_runtime.h>

#define N_NODES 50000
#define N_EDGES 600000
#define N_GRAPHS 500
#define F 128            // feature width for all conv layers
#define F4 (F/4)         // 32 float4 per row

// ---------------- degree / dinv ----------------
__global__ __launch_bounds__(256) void k_init_deg(float* deg, int n) {
    int i = blockIdx.x * 256 + threadIdx.x;
    if (i < n) deg[i] = 1.0f;  // self-loop
}

__global__ __launch_bounds__(256) void k_add_deg(const int* __restrict__ dst, float* deg, int ne) {
    int e = blockIdx.x * 256 + threadIdx.x;
    if (e < ne) unsafeAtomicAdd(&deg[dst[e]], 1.0f);
}

__global__ __launch_bounds__(256) void k_dinv(float* deg, int n) {
    int i = blockIdx.x * 256 + threadIdx.x;
    if (i < n) deg[i] = 1.0f / sqrtf(deg[i]);   // deg >= 1 always (self-loops)
}

// ---------------- GEMM: T = X @ W  (X: [n,128], W: [128,128]) ----------------
// 64 rows/block, 256 threads; thread tile = 8 rows x 4 cols (one float4).
__global__ __launch_bounds__(256) void k_gemm128(const float* __restrict__ X,
                                                 const float* __restrict__ W,
                                                 float* __restrict__ T, int n_rows) {
    __shared__ float Xs[64 * F];    // 32 KB
    __shared__ float Ws[32 * F];    // 16 KB (k-chunk of 32)
    int tid  = threadIdx.x;
    int row0 = blockIdx.x * 64;

    // stage X rows (2048 float4)
    for (int i = tid; i < 64 * F4; i += 256) {
        int r = i >> 5;           // local row
        float4 v = make_float4(0.f, 0.f, 0.f, 0.f);
        if (row0 + r < n_rows) v = ((const float4*)(X + (size_t)(row0 + r) * F))[i & 31];
        ((float4*)Xs)[i] = v;
    }

    int c4 = tid & 31;   // col group (4 cols)
    int rg = tid >> 5;   // row group (8 rows)
    float4 acc[8];
    #pragma unroll
    for (int i = 0; i < 8; i++) acc[i] = make_float4(0.f, 0.f, 0.f, 0.f);

    for (int kc = 0; kc < 4; kc++) {
        __syncthreads();
        // stage W k-chunk: k in [kc*32, kc*32+32), 1024 float4
        for (int i = tid; i < 32 * F4; i += 256)
            ((float4*)Ws)[i] = ((const float4*)W)[kc * (32 * F4) + i];
        __syncthreads();
        #pragma unroll
        for (int kk = 0; kk < 32; kk++) {
            int k = kc * 32 + kk;
            float4 wv = ((float4*)(Ws + kk * F))[c4];
            #pragma unroll
            for (int i = 0; i < 8; i++) {
                float xv = Xs[(rg * 8 + i) * F + k];
                acc[i].x = fmaf(xv, wv.x, acc[i].x);
                acc[i].y = fmaf(xv, wv.y, acc[i].y);
                acc[i].z = fmaf(xv, wv.z, acc[i].z);
                acc[i].w = fmaf(xv, wv.w, acc[i].w);
            }
        }
    }
    #pragma unroll
    for (int i = 0; i < 8; i++) {
        int row = row0 + rg * 8 + i;
        if (row < n_rows) ((float4*)(T + (size_t)row * F))[c4] = acc[i];
    }
}

// ---------------- edge scatter: A[dst] += T[src] * dinv[src]*dinv[dst] ----------------
// 8 edges per 256-thread block; 32 lanes per edge, float4 per lane.
__global__ __launch_bounds__(256) void k_scatter(const int* __restrict__ src,
                                                 const int* __restrict__ dst,
                                                 const float* __restrict__ dinv,
                                                 const float* __restrict__ T,
                                                 float* __restrict__ A, int ne) {
    int lane = threadIdx.x & 31;
    int e    = blockIdx.x * 8 + (threadIdx.x >> 5);
    if (e >= ne) return;
    int s = src[e], d = dst[e];
    float w = dinv[s] * dinv[d];
    float4 v = ((const float4*)(T + (size_t)s * F))[lane];
    float* out = A + (size_t)d * F + lane * 4;
    unsafeAtomicAdd(out + 0, v.x * w);
    unsafeAtomicAdd(out + 1, v.y * w);
    unsafeAtomicAdd(out + 2, v.z * w);
    unsafeAtomicAdd(out + 3, v.w * w);
}

// ---------------- epilogue: H = relu(A + T*dinv^2 + b), in-place on A allowed ----------------
__global__ __launch_bounds__(256) void k_epilogue(const float* __restrict__ A,
                                                  const float* __restrict__ T,
                                                  const float* __restrict__ dinv,
                                                  const float* __restrict__ b,
                                                  float* __restrict__ H, int n) {
    int idx = blockIdx.x * 256 + threadIdx.x;   // per float4
    if (idx >= n * F4) return;
    int node = idx >> 5, c4 = idx & 31;
    float w = dinv[node]; w = w * w;
    float4 a  = ((const float4*)A)[idx];
    float4 t  = ((const float4*)T)[idx];
    float4 bb = ((const float4*)b)[c4];
    float4 r;
    r.x = fmaxf(fmaf(t.x, w, a.x) + bb.x, 0.f);
    r.y = fmaxf(fmaf(t.y, w, a.y) + bb.y, 0.f);
    r.z = fmaxf(fmaf(t.z, w, a.z) + bb.z, 0.f);
    r.w = fmaxf(fmaf(t.w, w, a.w) + bb.w, 0.f);
    ((float4*)H)[idx] = r;
}

// ---------------- pooling ----------------
__global__ __launch_bounds__(256) void k_pool_sum(const float* __restrict__ H,
                                                  const int* __restrict__ batch,
                                                  float* __restrict__ pool, int n) {
    int idx = blockIdx.x * 256 + threadIdx.x;   // per float4
    if (idx >= n * F4) return;
    int node = idx >> 5, c4 = idx & 31;
    int g = batch[node];
    float4 v = ((const float4*)H)[idx];
    float* p = pool + (size_t)g * F + c4 * 4;
    unsafeAtomicAdd(p + 0, v.x);
    unsafeAtomicAdd(p + 1, v.y);
    unsafeAtomicAdd(p + 2, v.z);
    unsafeAtomicAdd(p + 3, v.w);
}

__global__ __launch_bounds__(256) void k_count(const int* __restrict__ batch, float* cnt, int n) {
    int i = blockIdx.x * 256 + threadIdx.x;
    if (i < n) unsafeAtomicAdd(&cnt[batch[i]], 1.0f);
}

// ---------------- FC head: out[g] = relu(hg@Wf1+bf1) @ Wf2 + bf2 ----------------
__global__ __launch_bounds__(64) void k_fc(const float* __restrict__ pool,
                                           const float* __restrict__ cnt,
                                           const float* __restrict__ Wf1,
                                           const float* __restrict__ bf1,
                                           const float* __restrict__ Wf2,
                                           const float* __restrict__ bf2,
                                           float* __restrict__ out) {
    int g = blockIdx.x;
    int j = threadIdx.x;          // 0..63
    __shared__ float hg[F];
    float c = fmaxf(cnt[g], 1.0f);
    hg[j]      = pool[(size_t)g * F + j] / c;
    hg[j + 64] = pool[(size_t)g * F + 64 + j] / c;
    __syncthreads();
    float acc = bf1[j];
    #pragma unroll 4
    for (int f = 0; f < F; f++) acc = fmaf(hg[f], Wf1[f * 64 + j], acc);
    float v = fmaxf(acc, 0.f) * Wf2[j];
    #pragma unroll
    for (int off = 32; off > 0; off >>= 1) v += __shfl_down(v, off, 64);
    if (j == 0) out[g] = v + bf2[0];
}

extern "C" void kernel_launch(void* const* d_in, const int* in_sizes, int n_in,
                              void* d_out, int out_size, void* d_ws, size_t ws_size,
                              hipStream_t stream) {
    const float* x    = (const float*)d_in[0];
    const int* eidx   = (const int*)d_in[1];
    const int* batch  = (const int*)d_in[2];
    const float* W1   = (const float*)d_in[3];
    const float* b1   = (const float*)d_in[4];
    const float* W2   = (const float*)d_in[5];
    const float* b2   = (const float*)d_in[6];
    const float* W3   = (const float*)d_in[7];
    const float* b3   = (const float*)d_in[8];
    const float* Wf1  = (const float*)d_in[9];
    const float* bf1  = (const float*)d_in[10];
    const float* Wf2  = (const float*)d_in[11];
    const float* bf2  = (const float*)d_in[12];
    float* out = (float*)d_out;

    const int* src = eidx;
    const int* dst = eidx + N_EDGES;

    // workspace layout (floats)
    float* ws   = (float*)d_ws;
    float* T    = ws;                       // 50000*128
    float* A    = T + (size_t)N_NODES * F;  // 50000*128
    float* B    = A + (size_t)N_NODES * F;  // 50000*128
    float* dinv = B + (size_t)N_NODES * F;  // 50000
    float* pool = dinv + N_NODES;           // 500*128
    float* cnt  = pool + (size_t)N_GRAPHS * F; // 500  (adjacent to pool for one memset)

    const size_t rowBytes = (size_t)N_NODES * F * sizeof(float);

    dim3 b256(256);
    int gNodes   = (N_NODES + 255) / 256;
    int gEdges   = (N_EDGES + 255) / 256;
    int gGemm    = (N_NODES + 63) / 64;
    int gScatter = (N_EDGES + 7) / 8;
    int gFeat    = (N_NODES * F4 + 255) / 256;

    // degree -> dinv (in place)
    k_init_deg<<<gNodes, b256, 0, stream>>>(dinv, N_NODES);
    k_add_deg<<<gEdges, b256, 0, stream>>>(dst, dinv, N_EDGES);
    k_dinv<<<gNodes, b256, 0, stream>>>(dinv, N_NODES);

    // layer 1: x -> A
    k_gemm128<<<gGemm, b256, 0, stream>>>(x, W1, T, N_NODES);
    hipMemsetAsync(A, 0, rowBytes, stream);
    k_scatter<<<gScatter, b256, 0, stream>>>(src, dst, dinv, T, A, N_EDGES);
    k_epilogue<<<gFeat, b256, 0, stream>>>(A, T, dinv, b1, A, N_NODES);

    // layer 2: A -> B
    k_gemm128<<<gGemm, b256, 0, stream>>>(A, W2, T, N_NODES);
    hipMemsetAsync(B, 0, rowBytes, stream);
    k_scatter<<<gScatter, b256, 0, stream>>>(src, dst, dinv, T, B, N_EDGES);
    k_epilogue<<<gFeat, b256, 0, stream>>>(B, T, dinv, b2, B, N_NODES);

    // layer 3: B -> A
    k_gemm128<<<gGemm, b256, 0, stream>>>(B, W3, T, N_NODES);
    hipMemsetAsync(A, 0, rowBytes, stream);
    k_scatter<<<gScatter, b256, 0, stream>>>(src, dst, dinv, T, A, N_EDGES);
    k_epilogue<<<gFeat, b256, 0, stream>>>(A, T, dinv, b3, A, N_NODES);

    // pooling
    hipMemsetAsync(pool, 0, ((size_t)N_GRAPHS * F + N_GRAPHS) * sizeof(float), stream);
    k_pool_sum<<<gFeat, b256, 0, stream>>>(A, batch, pool, N_NODES);
    k_count<<<gNodes, b256, 0, stream>>>(batch, cnt, N_NODES);

    // FC head
    k_fc<<<N_GRAPHS, dim3(64), 0, stream>>>(pool, cnt, Wf1, bf1, Wf2, bf2, out);
}

// Round 2
// 536.271 us; speedup vs baseline: 6.4562x; 6.4562x over previous
//
#include <hip/hip_runtime.h>

#define N_NODES 50000
#define N_EDGES 600000
#define N_GRAPHS 500
#define F 128            // feature width for all conv layers
#define F4 (F/4)

// ================= CSR build =================
__global__ __launch_bounds__(256) void k_hist(const int* __restrict__ dst, int* __restrict__ cnt, int ne) {
    int e = blockIdx.x * 256 + threadIdx.x;
    if (e < ne) atomicAdd(&cnt[dst[e]], 1);
}

// dinv[i] = rsqrt(cnt[i] + 1)   (self-loop included)
__global__ __launch_bounds__(256) void k_dinv(const int* __restrict__ cnt, float* __restrict__ dinv, int n) {
    int i = blockIdx.x * 256 + threadIdx.x;
    if (i < n) dinv[i] = rsqrtf((float)(cnt[i] + 1));
}

// block-level exclusive scan of cnt -> row_ptr (partial), block totals -> blksums
__global__ __launch_bounds__(256) void k_scan1(const int* __restrict__ cnt, int* __restrict__ row_ptr,
                                               int* __restrict__ blksums, int n) {
    __shared__ int s[256];
    int i = blockIdx.x * 256 + threadIdx.x;
    int v = (i < n) ? cnt[i] : 0;
    s[threadIdx.x] = v;
    __syncthreads();
    for (int off = 1; off < 256; off <<= 1) {
        int t = (threadIdx.x >= off) ? s[threadIdx.x - off] : 0;
        __syncthreads();
        s[threadIdx.x] += t;
        __syncthreads();
    }
    if (i < n) row_ptr[i] = s[threadIdx.x] - v;        // exclusive within block
    if (threadIdx.x == 255) blksums[blockIdx.x] = s[255];
}

// single-block exclusive scan of blksums (nb <= 256)
__global__ __launch_bounds__(256) void k_scan2(int* __restrict__ blksums, int nb) {
    __shared__ int s[256];
    int v = (threadIdx.x < nb) ? blksums[threadIdx.x] : 0;
    s[threadIdx.x] = v;
    __syncthreads();
    for (int off = 1; off < 256; off <<= 1) {
        int t = (threadIdx.x >= off) ? s[threadIdx.x - off] : 0;
        __syncthreads();
        s[threadIdx.x] += t;
        __syncthreads();
    }
    if (threadIdx.x < nb) blksums[threadIdx.x] = s[threadIdx.x] - v;   // exclusive
}

__global__ __launch_bounds__(256) void k_scan3(int* __restrict__ row_ptr, const int* __restrict__ blksums,
                                               int n, int ne) {
    int i = blockIdx.x * 256 + threadIdx.x;
    if (i < n) row_ptr[i] += blksums[blockIdx.x];
    if (i == 0) row_ptr[n] = ne;
}

// place src of each edge into CSR slot of its dst
__global__ __launch_bounds__(256) void k_fill(const int* __restrict__ src, const int* __restrict__ dst,
                                              const int* __restrict__ row_ptr, int* __restrict__ cursor,
                                              int* __restrict__ esrc, int ne) {
    int e = blockIdx.x * 256 + threadIdx.x;
    if (e < ne) {
        int d = dst[e];
        int pos = row_ptr[d] + atomicAdd(&cursor[d], 1);
        esrc[pos] = src[e];
    }
}

// ================= GEMM: T = X @ W (X:[n,128], W:[128,128]) =================
__global__ __launch_bounds__(256) void k_gemm128(const float* __restrict__ X,
                                                 const float* __restrict__ W,
                                                 float* __restrict__ T, int n_rows) {
    __shared__ float Xs[64 * F];
    __shared__ float Ws[32 * F];
    int tid  = threadIdx.x;
    int row0 = blockIdx.x * 64;

    for (int i = tid; i < 64 * F4; i += 256) {
        int r = i >> 5;
        float4 v = make_float4(0.f, 0.f, 0.f, 0.f);
        if (row0 + r < n_rows) v = ((const float4*)(X + (size_t)(row0 + r) * F))[i & 31];
        ((float4*)Xs)[i] = v;
    }

    int c4 = tid & 31;
    int rg = tid >> 5;
    float4 acc[8];
    #pragma unroll
    for (int i = 0; i < 8; i++) acc[i] = make_float4(0.f, 0.f, 0.f, 0.f);

    for (int kc = 0; kc < 4; kc++) {
        __syncthreads();
        for (int i = tid; i < 32 * F4; i += 256)
            ((float4*)Ws)[i] = ((const float4*)W)[kc * (32 * F4) + i];
        __syncthreads();
        #pragma unroll
        for (int kk = 0; kk < 32; kk++) {
            int k = kc * 32 + kk;
            float4 wv = ((float4*)(Ws + kk * F))[c4];
            #pragma unroll
            for (int i = 0; i < 8; i++) {
                float xv = Xs[(rg * 8 + i) * F + k];
                acc[i].x = fmaf(xv, wv.x, acc[i].x);
                acc[i].y = fmaf(xv, wv.y, acc[i].y);
                acc[i].z = fmaf(xv, wv.z, acc[i].z);
                acc[i].w = fmaf(xv, wv.w, acc[i].w);
            }
        }
    }
    #pragma unroll
    for (int i = 0; i < 8; i++) {
        int row = row0 + rg * 8 + i;
        if (row < n_rows) ((float4*)(T + (size_t)row * F))[c4] = acc[i];
    }
}

// ============ fused gather + self-loop + bias + ReLU ============
// one wave (64 lanes) per dst node; lane handles one float2 (128 feats)
__global__ __launch_bounds__(256) void k_gather(const int* __restrict__ row_ptr,
                                                const int* __restrict__ esrc,
                                                const float* __restrict__ dinv,
                                                const float* __restrict__ T,
                                                const float* __restrict__ bias,
                                                float* __restrict__ H, int n) {
    int node = blockIdx.x * 4 + (threadIdx.x >> 6);
    int lane = threadIdx.x & 63;
    if (node >= n) return;
    int beg = row_ptr[node], end = row_ptr[node + 1];
    float dd = dinv[node];

    // self-loop term
    float2 v = ((const float2*)(T + (size_t)node * F))[lane];
    float ws = dd * dd;
    float2 acc;
    acc.x = v.x * ws;
    acc.y = v.y * ws;

    for (int e = beg; e < end; e++) {
        int s = esrc[e];
        float w = dinv[s] * dd;
        float2 t = ((const float2*)(T + (size_t)s * F))[lane];
        acc.x = fmaf(t.x, w, acc.x);
        acc.y = fmaf(t.y, w, acc.y);
    }
    float2 bb = ((const float2*)bias)[lane];
    float2 r;
    r.x = fmaxf(acc.x + bb.x, 0.f);
    r.y = fmaxf(acc.y + bb.y, 0.f);
    ((float2*)(H + (size_t)node * F))[lane] = r;
}

// ============ pooling: batch is sorted -> per-graph segment mean ============
__global__ __launch_bounds__(64) void k_pool(const float* __restrict__ H,
                                             const int* __restrict__ batch,
                                             float* __restrict__ pool) {
    int g = blockIdx.x;
    int lane = threadIdx.x;   // 0..63
    // lower_bound(batch, g)
    int lo = 0, hi = N_NODES;
    while (lo < hi) { int mid = (lo + hi) >> 1; if (batch[mid] < g) lo = mid + 1; else hi = mid; }
    int start = lo;
    lo = start; hi = N_NODES;
    while (lo < hi) { int mid = (lo + hi) >> 1; if (batch[mid] < g + 1) lo = mid + 1; else hi = mid; }
    int end = lo;

    float2 acc = make_float2(0.f, 0.f);
    for (int i = start; i < end; i++) {
        float2 v = ((const float2*)(H + (size_t)i * F))[lane];
        acc.x += v.x; acc.y += v.y;
    }
    int cnt = end - start;
    float inv = 1.0f / (float)(cnt > 0 ? cnt : 1);
    float2 r; r.x = acc.x * inv; r.y = acc.y * inv;
    ((float2*)(pool + (size_t)g * F))[lane] = r;
}

// ============ FC head ============
__global__ __launch_bounds__(64) void k_fc(const float* __restrict__ pool,
                                           const float* __restrict__ Wf1,
                                           const float* __restrict__ bf1,
                                           const float* __restrict__ Wf2,
                                           const float* __restrict__ bf2,
                                           float* __restrict__ out) {
    int g = blockIdx.x;
    int j = threadIdx.x;          // 0..63
    __shared__ float hg[F];
    hg[j]      = pool[(size_t)g * F + j];
    hg[j + 64] = pool[(size_t)g * F + 64 + j];
    __syncthreads();
    float acc = bf1[j];
    #pragma unroll 4
    for (int f = 0; f < F; f++) acc = fmaf(hg[f], Wf1[f * 64 + j], acc);
    float v = fmaxf(acc, 0.f) * Wf2[j];
    #pragma unroll
    for (int off = 32; off > 0; off >>= 1) v += __shfl_down(v, off, 64);
    if (j == 0) out[g] = v + bf2[0];
}

extern "C" void kernel_launch(void* const* d_in, const int* in_sizes, int n_in,
                              void* d_out, int out_size, void* d_ws, size_t ws_size,
                              hipStream_t stream) {
    const float* x    = (const float*)d_in[0];
    const int* eidx   = (const int*)d_in[1];
    const int* batch  = (const int*)d_in[2];
    const float* W1   = (const float*)d_in[3];
    const float* b1   = (const float*)d_in[4];
    const float* W2   = (const float*)d_in[5];
    const float* b2   = (const float*)d_in[6];
    const float* W3   = (const float*)d_in[7];
    const float* b3   = (const float*)d_in[8];
    const float* Wf1  = (const float*)d_in[9];
    const float* bf1  = (const float*)d_in[10];
    const float* Wf2  = (const float*)d_in[11];
    const float* bf2  = (const float*)d_in[12];
    float* out = (float*)d_out;

    const int* src = eidx;
    const int* dst = eidx + N_EDGES;

    // workspace layout
    char* p = (char*)d_ws;
    float* T    = (float*)p;               p += (size_t)N_NODES * F * sizeof(float);
    float* A    = (float*)p;               p += (size_t)N_NODES * F * sizeof(float);
    float* B    = (float*)p;               p += (size_t)N_NODES * F * sizeof(float);
    float* dinv = (float*)p;               p += (size_t)N_NODES * sizeof(float);
    float* pool = (float*)p;               p += (size_t)N_GRAPHS * F * sizeof(float);
    int* cnt     = (int*)p;                p += (size_t)N_NODES * sizeof(int);
    int* row_ptr = (int*)p;                p += (size_t)(N_NODES + 1) * sizeof(int);
    int* blksums = (int*)p;                p += 256 * sizeof(int);
    int* esrc    = (int*)p;                p += (size_t)N_EDGES * sizeof(int);

    dim3 b256(256);
    int gNodes   = (N_NODES + 255) / 256;   // 196
    int gEdges   = (N_EDGES + 255) / 256;
    int gGemm    = (N_NODES + 63) / 64;
    int gGather  = (N_NODES + 3) / 4;

    // ---- CSR build (once per call) ----
    hipMemsetAsync(cnt, 0, (size_t)N_NODES * sizeof(int), stream);
    k_hist<<<gEdges, b256, 0, stream>>>(dst, cnt, N_EDGES);
    k_dinv<<<gNodes, b256, 0, stream>>>(cnt, dinv, N_NODES);
    k_scan1<<<gNodes, b256, 0, stream>>>(cnt, row_ptr, blksums, N_NODES);
    k_scan2<<<1, b256, 0, stream>>>(blksums, gNodes);
    k_scan3<<<gNodes, b256, 0, stream>>>(row_ptr, blksums, N_NODES, N_EDGES);
    hipMemsetAsync(cnt, 0, (size_t)N_NODES * sizeof(int), stream);   // reuse as cursor
    k_fill<<<gEdges, b256, 0, stream>>>(src, dst, row_ptr, cnt, esrc, N_EDGES);

    // ---- layer 1: x -> A ----
    k_gemm128<<<gGemm, b256, 0, stream>>>(x, W1, T, N_NODES);
    k_gather<<<gGather, b256, 0, stream>>>(row_ptr, esrc, dinv, T, b1, A, N_NODES);

    // ---- layer 2: A -> B ----
    k_gemm128<<<gGemm, b256, 0, stream>>>(A, W2, T, N_NODES);
    k_gather<<<gGather, b256, 0, stream>>>(row_ptr, esrc, dinv, T, b2, B, N_NODES);

    // ---- layer 3: B -> A ----
    k_gemm128<<<gGemm, b256, 0, stream>>>(B, W3, T, N_NODES);
    k_gather<<<gGather, b256, 0, stream>>>(row_ptr, esrc, dinv, T, b3, A, N_NODES);

    // ---- pooling (batch sorted -> segment mean, no atomics) ----
    k_pool<<<N_GRAPHS, dim3(64), 0, stream>>>(A, batch, pool);

    // ---- FC head ----
    k_fc<<<N_GRAPHS, dim3(64), 0, stream>>>(pool, Wf1, bf1, Wf2, bf2, out);
}

// Round 3
// 417.516 us; speedup vs baseline: 8.2925x; 1.2844x over previous
//
#include <hip/hip_runtime.h>

#define N_NODES 50000
#define N_EDGES 600000
#define N_GRAPHS 500
#define F 128
#define F4 (F/4)

// ================= CSR build =================
__global__ __launch_bounds__(256) void k_hist(const int* __restrict__ dst, int* __restrict__ cnt, int ne) {
    int e = blockIdx.x * 256 + threadIdx.x;
    if (e < ne) atomicAdd(&cnt[dst[e]], 1);
}

// block-level exclusive scan of cnt -> row_ptr (partial), block totals -> blksums; also dinv
__global__ __launch_bounds__(256) void k_scan1(const int* __restrict__ cnt, int* __restrict__ row_ptr,
                                               int* __restrict__ blksums, float* __restrict__ dinv, int n) {
    __shared__ int s[256];
    int i = blockIdx.x * 256 + threadIdx.x;
    int v = (i < n) ? cnt[i] : 0;
    if (i < n) dinv[i] = rsqrtf((float)(v + 1));   // self-loop included
    s[threadIdx.x] = v;
    __syncthreads();
    for (int off = 1; off < 256; off <<= 1) {
        int t = (threadIdx.x >= off) ? s[threadIdx.x - off] : 0;
        __syncthreads();
        s[threadIdx.x] += t;
        __syncthreads();
    }
    if (i < n) row_ptr[i] = s[threadIdx.x] - v;
    if (threadIdx.x == 255) blksums[blockIdx.x] = s[255];
}

__global__ __launch_bounds__(256) void k_scan2(int* __restrict__ blksums, int nb) {
    __shared__ int s[256];
    int v = (threadIdx.x < nb) ? blksums[threadIdx.x] : 0;
    s[threadIdx.x] = v;
    __syncthreads();
    for (int off = 1; off < 256; off <<= 1) {
        int t = (threadIdx.x >= off) ? s[threadIdx.x - off] : 0;
        __syncthreads();
        s[threadIdx.x] += t;
        __syncthreads();
    }
    if (threadIdx.x < nb) blksums[threadIdx.x] = s[threadIdx.x] - v;
}

__global__ __launch_bounds__(256) void k_scan3(int* __restrict__ row_ptr, const int* __restrict__ blksums,
                                               int n, int ne) {
    int i = blockIdx.x * 256 + threadIdx.x;
    if (i < n) row_ptr[i] += blksums[blockIdx.x];
    if (i == 0) row_ptr[n] = ne;
}

__global__ __launch_bounds__(256) void k_fill(const int* __restrict__ src, const int* __restrict__ dst,
                                              const int* __restrict__ row_ptr, int* __restrict__ cursor,
                                              int* __restrict__ esrc, int ne) {
    int e = blockIdx.x * 256 + threadIdx.x;
    if (e < ne) {
        int d = dst[e];
        int pos = row_ptr[d] + atomicAdd(&cursor[d], 1);
        esrc[pos] = src[e];
    }
}

// ================= GEMM: T = X @ W (X:[n,128], W:[128,128]) =================
// 64-row tile, 256 threads, thread tile 4 rows x 8 cols. k-major LDS, all b128 reads.
#define TM 64
#define FMA4(A, S, Wv) { A.x = fmaf(S, Wv.x, A.x); A.y = fmaf(S, Wv.y, A.y); \
                         A.z = fmaf(S, Wv.z, A.z); A.w = fmaf(S, Wv.w, A.w); }

__global__ __launch_bounds__(256) void k_gemm128(const float* __restrict__ X,
                                                 const float* __restrict__ W,
                                                 float* __restrict__ T, int n_rows) {
    __shared__ float Xs[32 * TM];   // [kk][row]  8 KB
    __shared__ float Ws[32 * F];    // [kk][col] 16 KB
    int tid  = threadIdx.x;
    int row0 = blockIdx.x * TM;
    int cg = tid & 15;        // col group -> cols cg*4..+3 and +64
    int rg = tid >> 4;        // row group -> rows rg*4..+3
    int j0 = cg * 4;
    int r0 = rg * 4;
    // staging map: 4 threads per row, each 8 k-values (2 float4)
    int srow = tid >> 2;            // 0..63
    int skb  = (tid & 3) * 8;       // k base
    bool rvalid = (row0 + srow) < n_rows;
    const float* Xrow = X + (size_t)(row0 + srow) * F;

    float4 accA[4], accB[4];
    #pragma unroll
    for (int i = 0; i < 4; i++) { accA[i] = make_float4(0,0,0,0); accB[i] = make_float4(0,0,0,0); }

    for (int kc = 0; kc < 4; ++kc) {
        __syncthreads();
        // stage W chunk [kc*32 .. +32) x 128 : 1024 float4
        #pragma unroll
        for (int q = 0; q < 4; ++q) {
            int i = tid + 256 * q;
            ((float4*)Ws)[i] = ((const float4*)(W + (size_t)kc * 32 * F))[i];
        }
        // stage X chunk with transpose -> Xs[k][row]
        float4 xv0 = make_float4(0,0,0,0), xv1 = make_float4(0,0,0,0);
        if (rvalid) {
            xv0 = ((const float4*)(Xrow + kc * 32 + skb))[0];
            xv1 = ((const float4*)(Xrow + kc * 32 + skb))[1];
        }
        Xs[(skb + 0) * TM + srow] = xv0.x;
        Xs[(skb + 1) * TM + srow] = xv0.y;
        Xs[(skb + 2) * TM + srow] = xv0.z;
        Xs[(skb + 3) * TM + srow] = xv0.w;
        Xs[(skb + 4) * TM + srow] = xv1.x;
        Xs[(skb + 5) * TM + srow] = xv1.y;
        Xs[(skb + 6) * TM + srow] = xv1.z;
        Xs[(skb + 7) * TM + srow] = xv1.w;
        __syncthreads();
        #pragma unroll
        for (int kk = 0; kk < 32; ++kk) {
            float4 xa = *(const float4*)&Xs[kk * TM + r0];
            float4 wa = *(const float4*)&Ws[kk * F + j0];
            float4 wb = *(const float4*)&Ws[kk * F + j0 + 64];
            FMA4(accA[0], xa.x, wa); FMA4(accB[0], xa.x, wb);
            FMA4(accA[1], xa.y, wa); FMA4(accB[1], xa.y, wb);
            FMA4(accA[2], xa.z, wa); FMA4(accB[2], xa.z, wb);
            FMA4(accA[3], xa.w, wa); FMA4(accB[3], xa.w, wb);
        }
    }
    #pragma unroll
    for (int i = 0; i < 4; ++i) {
        int row = row0 + r0 + i;
        if (row < n_rows) {
            ((float4*)(T + (size_t)row * F))[cg]      = accA[i];
            ((float4*)(T + (size_t)row * F))[cg + 16] = accB[i];
        }
    }
}

// ============ fused gather + self-loop + bias + ReLU ============
// one wave per node; two half-waves process 2 edges/iter (float4 per lane);
// indices prefetched 2 iters ahead, row 1 iter ahead. Self-loop = virtual edge at `end`.
__global__ __launch_bounds__(256) void k_gather(const int* __restrict__ row_ptr,
                                                const int* __restrict__ esrc,
                                                const float* __restrict__ dinv,
                                                const float* __restrict__ T,
                                                const float* __restrict__ bias,
                                                float* __restrict__ H, int n) {
    int node = blockIdx.x * 4 + (threadIdx.x >> 6);
    if (node >= n) return;
    int lane = threadIdx.x & 63;
    int half = lane >> 5;
    int sub  = lane & 31;
    int beg = row_ptr[node], end = row_ptr[node + 1];
    float dd = dinv[node];

    int m = end - beg + 1;          // incl. virtual self edge at index `end`
    int iters = (m + 1) >> 1;

    int e = beg + half;
    int s0; float w0;
    if (e < end)       { s0 = esrc[e]; w0 = dinv[s0] * dd; }
    else if (e == end) { s0 = node;    w0 = dd * dd; }
    else               { s0 = node;    w0 = 0.f; }
    float4 t0 = ((const float4*)(T + (size_t)s0 * F))[sub];

    int eN = e + 2;
    int s1; float w1;
    if (eN < end)       { s1 = esrc[eN]; w1 = dinv[s1] * dd; }
    else if (eN == end) { s1 = node;     w1 = dd * dd; }
    else                { s1 = node;     w1 = 0.f; }

    float4 acc = make_float4(0,0,0,0);
    for (int it = 1; it < iters; ++it) {
        float4 t1 = ((const float4*)(T + (size_t)s1 * F))[sub];
        eN += 2;
        int s2; float w2;
        if (eN < end)       { s2 = esrc[eN]; w2 = dinv[s2] * dd; }
        else if (eN == end) { s2 = node;     w2 = dd * dd; }
        else                { s2 = node;     w2 = 0.f; }
        acc.x = fmaf(t0.x, w0, acc.x);
        acc.y = fmaf(t0.y, w0, acc.y);
        acc.z = fmaf(t0.z, w0, acc.z);
        acc.w = fmaf(t0.w, w0, acc.w);
        t0 = t1; w0 = w1; s1 = s2; w1 = w2;
    }
    acc.x = fmaf(t0.x, w0, acc.x);
    acc.y = fmaf(t0.y, w0, acc.y);
    acc.z = fmaf(t0.z, w0, acc.z);
    acc.w = fmaf(t0.w, w0, acc.w);

    // combine the two half-wave partials
    acc.x += __shfl_xor(acc.x, 32, 64);
    acc.y += __shfl_xor(acc.y, 32, 64);
    acc.z += __shfl_xor(acc.z, 32, 64);
    acc.w += __shfl_xor(acc.w, 32, 64);

    if (half == 0) {
        float4 bb = ((const float4*)bias)[sub];
        float4 r;
        r.x = fmaxf(acc.x + bb.x, 0.f);
        r.y = fmaxf(acc.y + bb.y, 0.f);
        r.z = fmaxf(acc.z + bb.z, 0.f);
        r.w = fmaxf(acc.w + bb.w, 0.f);
        ((float4*)(H + (size_t)node * F))[sub] = r;
    }
}

// ============ fused pool (segment mean) + FC head ============
__global__ __launch_bounds__(256) void k_pool_fc(const float* __restrict__ H,
                                                 const int* __restrict__ batch,
                                                 const float* __restrict__ Wf1,
                                                 const float* __restrict__ bf1,
                                                 const float* __restrict__ Wf2,
                                                 const float* __restrict__ bf2,
                                                 float* __restrict__ out) {
    int g = blockIdx.x;
    int tid = threadIdx.x;
    // segment bounds (batch sorted)
    int lo = 0, hi = N_NODES;
    while (lo < hi) { int mid = (lo + hi) >> 1; if (batch[mid] < g) lo = mid + 1; else hi = mid; }
    int start = lo;
    hi = N_NODES;
    while (lo < hi) { int mid = (lo + hi) >> 1; if (batch[mid] <= g) lo = mid + 1; else hi = mid; }
    int end = lo;

    __shared__ float hs[4][F];
    __shared__ float hg[F];
    int wv = tid >> 6, lane = tid & 63;
    float2 a = make_float2(0.f, 0.f);
    for (int i = start + wv; i < end; i += 4) {
        float2 v = ((const float2*)(H + (size_t)i * F))[lane];
        a.x += v.x; a.y += v.y;
    }
    hs[wv][lane * 2]     = a.x;
    hs[wv][lane * 2 + 1] = a.y;
    __syncthreads();
    if (tid < F) {
        float inv = 1.0f / (float)((end - start) > 0 ? (end - start) : 1);
        hg[tid] = (hs[0][tid] + hs[1][tid] + hs[2][tid] + hs[3][tid]) * inv;
    }
    __syncthreads();
    if (tid < 64) {
        float acc = bf1[tid];
        #pragma unroll 4
        for (int f = 0; f < F; ++f) acc = fmaf(hg[f], Wf1[f * 64 + tid], acc);
        float v = fmaxf(acc, 0.f) * Wf2[tid];
        #pragma unroll
        for (int off = 32; off > 0; off >>= 1) v += __shfl_down(v, off, 64);
        if (tid == 0) out[g] = v + bf2[0];
    }
}

extern "C" void kernel_launch(void* const* d_in, const int* in_sizes, int n_in,
                              void* d_out, int out_size, void* d_ws, size_t ws_size,
                              hipStream_t stream) {
    const float* x    = (const float*)d_in[0];
    const int* eidx   = (const int*)d_in[1];
    const int* batch  = (const int*)d_in[2];
    const float* W1   = (const float*)d_in[3];
    const float* b1   = (const float*)d_in[4];
    const float* W2   = (const float*)d_in[5];
    const float* b2   = (const float*)d_in[6];
    const float* W3   = (const float*)d_in[7];
    const float* b3   = (const float*)d_in[8];
    const float* Wf1  = (const float*)d_in[9];
    const float* bf1  = (const float*)d_in[10];
    const float* Wf2  = (const float*)d_in[11];
    const float* bf2  = (const float*)d_in[12];
    float* out = (float*)d_out;

    const int* src = eidx;
    const int* dst = eidx + N_EDGES;

    char* p = (char*)d_ws;
    float* T    = (float*)p;   p += (size_t)N_NODES * F * sizeof(float);
    float* A    = (float*)p;   p += (size_t)N_NODES * F * sizeof(float);
    float* B    = (float*)p;   p += (size_t)N_NODES * F * sizeof(float);
    float* dinv = (float*)p;   p += (size_t)N_NODES * sizeof(float);
    int* cnt     = (int*)p;    p += (size_t)N_NODES * sizeof(int);
    int* row_ptr = (int*)p;    p += (size_t)(N_NODES + 1) * sizeof(int);
    int* blksums = (int*)p;    p += 256 * sizeof(int);
    int* esrc    = (int*)p;    p += (size_t)N_EDGES * sizeof(int);

    dim3 b256(256);
    int gNodes   = (N_NODES + 255) / 256;
    int gEdges   = (N_EDGES + 255) / 256;
    int gGemm    = (N_NODES + TM - 1) / TM;
    int gGather  = (N_NODES + 3) / 4;

    // ---- CSR build ----
    hipMemsetAsync(cnt, 0, (size_t)N_NODES * sizeof(int), stream);
    k_hist<<<gEdges, b256, 0, stream>>>(dst, cnt, N_EDGES);
    k_scan1<<<gNodes, b256, 0, stream>>>(cnt, row_ptr, blksums, dinv, N_NODES);
    k_scan2<<<1, b256, 0, stream>>>(blksums, gNodes);
    k_scan3<<<gNodes, b256, 0, stream>>>(row_ptr, blksums, N_NODES, N_EDGES);
    hipMemsetAsync(cnt, 0, (size_t)N_NODES * sizeof(int), stream);
    k_fill<<<gEdges, b256, 0, stream>>>(src, dst, row_ptr, cnt, esrc, N_EDGES);

    // ---- layer 1: x -> A ----
    k_gemm128<<<gGemm, b256, 0, stream>>>(x, W1, T, N_NODES);
    k_gather<<<gGather, b256, 0, stream>>>(row_ptr, esrc, dinv, T, b1, A, N_NODES);

    // ---- layer 2: A -> B ----
    k_gemm128<<<gGemm, b256, 0, stream>>>(A, W2, T, N_NODES);
    k_gather<<<gGather, b256, 0, stream>>>(row_ptr, esrc, dinv, T, b2, B, N_NODES);

    // ---- layer 3: B -> A ----
    k_gemm128<<<gGemm, b256, 0, stream>>>(B, W3, T, N_NODES);
    k_gather<<<gGather, b256, 0, stream>>>(row_ptr, esrc, dinv, T, b3, A, N_NODES);

    // ---- pool + FC ----
    k_pool_fc<<<N_GRAPHS, b256, 0, stream>>>(A, batch, Wf1, bf1, Wf2, bf2, out);
}

// Round 4
// 393.036 us; speedup vs baseline: 8.8090x; 1.0623x over previous
//
#include <hip/hip_runtime.h>

#define N_NODES 50000
#define N_EDGES 600000
#define N_GRAPHS 500
#define F 128
#define F4 (F/4)

// ================= CSR build =================
__global__ __launch_bounds__(256) void k_hist(const int* __restrict__ dst, int* __restrict__ cnt, int ne) {
    int e = blockIdx.x * 256 + threadIdx.x;
    if (e < ne) atomicAdd(&cnt[dst[e]], 1);
}

__global__ __launch_bounds__(256) void k_scan1(const int* __restrict__ cnt, int* __restrict__ row_ptr,
                                               int* __restrict__ blksums, float* __restrict__ dinv, int n) {
    __shared__ int s[256];
    int i = blockIdx.x * 256 + threadIdx.x;
    int v = (i < n) ? cnt[i] : 0;
    if (i < n) dinv[i] = rsqrtf((float)(v + 1));   // self-loop included
    s[threadIdx.x] = v;
    __syncthreads();
    for (int off = 1; off < 256; off <<= 1) {
        int t = (threadIdx.x >= off) ? s[threadIdx.x - off] : 0;
        __syncthreads();
        s[threadIdx.x] += t;
        __syncthreads();
    }
    if (i < n) row_ptr[i] = s[threadIdx.x] - v;
    if (threadIdx.x == 255) blksums[blockIdx.x] = s[255];
}

__global__ __launch_bounds__(256) void k_scan2(int* __restrict__ blksums, int nb) {
    __shared__ int s[256];
    int v = (threadIdx.x < nb) ? blksums[threadIdx.x] : 0;
    s[threadIdx.x] = v;
    __syncthreads();
    for (int off = 1; off < 256; off <<= 1) {
        int t = (threadIdx.x >= off) ? s[threadIdx.x - off] : 0;
        __syncthreads();
        s[threadIdx.x] += t;
        __syncthreads();
    }
    if (threadIdx.x < nb) blksums[threadIdx.x] = s[threadIdx.x] - v;
}

__global__ __launch_bounds__(256) void k_scan3(int* __restrict__ row_ptr, const int* __restrict__ blksums,
                                               int n, int ne) {
    int i = blockIdx.x * 256 + threadIdx.x;
    if (i < n) row_ptr[i] += blksums[blockIdx.x];
    if (i == 0) row_ptr[n] = ne;
}

// count-down fill: cnt holds degrees on entry (consumed here)
__global__ __launch_bounds__(256) void k_fill(const int* __restrict__ src, const int* __restrict__ dst,
                                              const int* __restrict__ row_ptr, int* __restrict__ cnt,
                                              int* __restrict__ esrc, int ne) {
    int e = blockIdx.x * 256 + threadIdx.x;
    if (e < ne) {
        int d = dst[e];
        int pos = row_ptr[d] + atomicSub(&cnt[d], 1) - 1;
        esrc[pos] = src[e];
    }
}

// ================= GEMM: T = X @ W (X:[n,128], W:[128,128]) =================
#define TM 64
#define FMA4(A, S, Wv) { A.x = fmaf(S, Wv.x, A.x); A.y = fmaf(S, Wv.y, A.y); \
                         A.z = fmaf(S, Wv.z, A.z); A.w = fmaf(S, Wv.w, A.w); }

__global__ __launch_bounds__(256) void k_gemm128(const float* __restrict__ X,
                                                 const float* __restrict__ W,
                                                 float* __restrict__ T, int n_rows) {
    __shared__ float Xs[32 * TM];   // [kk][row]
    __shared__ float Ws[32 * F];    // [kk][col]
    int tid  = threadIdx.x;
    int row0 = blockIdx.x * TM;
    int cg = tid & 15;
    int rg = tid >> 4;
    int j0 = cg * 4;
    int r0 = rg * 4;
    int srow = tid >> 2;
    int skb  = (tid & 3) * 8;
    bool rvalid = (row0 + srow) < n_rows;
    const float* Xrow = X + (size_t)(row0 + srow) * F;

    float4 accA[4], accB[4];
    #pragma unroll
    for (int i = 0; i < 4; i++) { accA[i] = make_float4(0,0,0,0); accB[i] = make_float4(0,0,0,0); }

    for (int kc = 0; kc < 4; ++kc) {
        __syncthreads();
        #pragma unroll
        for (int q = 0; q < 4; ++q) {
            int i = tid + 256 * q;
            ((float4*)Ws)[i] = ((const float4*)(W + (size_t)kc * 32 * F))[i];
        }
        float4 xv0 = make_float4(0,0,0,0), xv1 = make_float4(0,0,0,0);
        if (rvalid) {
            xv0 = ((const float4*)(Xrow + kc * 32 + skb))[0];
            xv1 = ((const float4*)(Xrow + kc * 32 + skb))[1];
        }
        Xs[(skb + 0) * TM + srow] = xv0.x;
        Xs[(skb + 1) * TM + srow] = xv0.y;
        Xs[(skb + 2) * TM + srow] = xv0.z;
        Xs[(skb + 3) * TM + srow] = xv0.w;
        Xs[(skb + 4) * TM + srow] = xv1.x;
        Xs[(skb + 5) * TM + srow] = xv1.y;
        Xs[(skb + 6) * TM + srow] = xv1.z;
        Xs[(skb + 7) * TM + srow] = xv1.w;
        __syncthreads();
        #pragma unroll
        for (int kk = 0; kk < 32; ++kk) {
            float4 xa = *(const float4*)&Xs[kk * TM + r0];
            float4 wa = *(const float4*)&Ws[kk * F + j0];
            float4 wb = *(const float4*)&Ws[kk * F + j0 + 64];
            FMA4(accA[0], xa.x, wa); FMA4(accB[0], xa.x, wb);
            FMA4(accA[1], xa.y, wa); FMA4(accB[1], xa.y, wb);
            FMA4(accA[2], xa.z, wa); FMA4(accB[2], xa.z, wb);
            FMA4(accA[3], xa.w, wa); FMA4(accB[3], xa.w, wb);
        }
    }
    #pragma unroll
    for (int i = 0; i < 4; ++i) {
        int row = row0 + r0 + i;
        if (row < n_rows) {
            ((float4*)(T + (size_t)row * F))[cg]      = accA[i];
            ((float4*)(T + (size_t)row * F))[cg + 16] = accB[i];
        }
    }
}

// ============ fused gather + self-loop + bias + ReLU ============
// one wave per node; 4 quarter-waves process 4 edges/iter (16 lanes x 2 float4 each);
// edge indices prefetched one iteration ahead. Self-loop = virtual edge at `end`.
__global__ __launch_bounds__(256) void k_gather(const int* __restrict__ row_ptr,
                                                const int* __restrict__ esrc,
                                                const float* __restrict__ dinv,
                                                const float* __restrict__ T,
                                                const float* __restrict__ bias,
                                                float* __restrict__ H, int n) {
    int node = blockIdx.x * 4 + (threadIdx.x >> 6);
    if (node >= n) return;
    int lane = threadIdx.x & 63;
    int q    = lane >> 4;
    int sub  = lane & 15;
    int beg = row_ptr[node], end = row_ptr[node + 1];
    float dd = dinv[node];

    int m = end - beg + 1;          // incl. virtual self edge
    int iters = (m + 3) >> 2;

    int e1 = beg + q;
    int s0; float w0;
    if (e1 < end)       { s0 = esrc[e1]; w0 = dinv[s0] * dd; }
    else if (e1 == end) { s0 = node;     w0 = dd * dd; }
    else                { s0 = node;     w0 = 0.f; }
    const float4* rp0 = (const float4*)(T + (size_t)s0 * F);
    float4 lo0 = rp0[sub], hi0 = rp0[sub + 16];

    e1 += 4;
    int s1; float w1;
    if (e1 < end)       { s1 = esrc[e1]; w1 = dinv[s1] * dd; }
    else if (e1 == end) { s1 = node;     w1 = dd * dd; }
    else                { s1 = node;     w1 = 0.f; }

    float4 accL = make_float4(0,0,0,0), accH = make_float4(0,0,0,0);
    for (int it = 1; it < iters; ++it) {
        const float4* rp = (const float4*)(T + (size_t)s1 * F);
        float4 lo1 = rp[sub], hi1 = rp[sub + 16];
        int e2 = e1 + 4;
        int s2; float w2;
        if (e2 < end)       { s2 = esrc[e2]; w2 = dinv[s2] * dd; }
        else if (e2 == end) { s2 = node;     w2 = dd * dd; }
        else                { s2 = node;     w2 = 0.f; }
        FMA4(accL, w0, lo0);
        FMA4(accH, w0, hi0);
        lo0 = lo1; hi0 = hi1; w0 = w1;
        w1 = w2; s1 = s2; e1 = e2;
    }
    FMA4(accL, w0, lo0);
    FMA4(accH, w0, hi0);

    // combine quarter-wave partials (xor 16, then xor 32)
    accL.x += __shfl_xor(accL.x, 16, 64); accH.x += __shfl_xor(accH.x, 16, 64);
    accL.y += __shfl_xor(accL.y, 16, 64); accH.y += __shfl_xor(accH.y, 16, 64);
    accL.z += __shfl_xor(accL.z, 16, 64); accH.z += __shfl_xor(accH.z, 16, 64);
    accL.w += __shfl_xor(accL.w, 16, 64); accH.w += __shfl_xor(accH.w, 16, 64);
    accL.x += __shfl_xor(accL.x, 32, 64); accH.x += __shfl_xor(accH.x, 32, 64);
    accL.y += __shfl_xor(accL.y, 32, 64); accH.y += __shfl_xor(accH.y, 32, 64);
    accL.z += __shfl_xor(accL.z, 32, 64); accH.z += __shfl_xor(accH.z, 32, 64);
    accL.w += __shfl_xor(accL.w, 32, 64); accH.w += __shfl_xor(accH.w, 32, 64);

    if (lane < 32) {
        // lane 0..15 -> chunk lane (accL); lane 16..31 -> chunk lane (accH since sub+16==lane)
        float4 v = (lane < 16) ? accL : accH;
        float4 bb = ((const float4*)bias)[lane];
        float4 r;
        r.x = fmaxf(v.x + bb.x, 0.f);
        r.y = fmaxf(v.y + bb.y, 0.f);
        r.z = fmaxf(v.z + bb.z, 0.f);
        r.w = fmaxf(v.w + bb.w, 0.f);
        ((float4*)(H + (size_t)node * F))[lane] = r;
    }
}

// ============ fused pool (segment mean) + FC head ============
__global__ __launch_bounds__(256) void k_pool_fc(const float* __restrict__ H,
                                                 const int* __restrict__ batch,
                                                 const float* __restrict__ Wf1,
                                                 const float* __restrict__ bf1,
                                                 const float* __restrict__ Wf2,
                                                 const float* __restrict__ bf2,
                                                 float* __restrict__ out) {
    int g = blockIdx.x;
    int tid = threadIdx.x;
    int lo = 0, hi = N_NODES;
    while (lo < hi) { int mid = (lo + hi) >> 1; if (batch[mid] < g) lo = mid + 1; else hi = mid; }
    int start = lo;
    hi = N_NODES;
    while (lo < hi) { int mid = (lo + hi) >> 1; if (batch[mid] <= g) lo = mid + 1; else hi = mid; }
    int end = lo;

    __shared__ float hs[4][F];
    __shared__ float hg[F];
    int wv = tid >> 6, lane = tid & 63;
    int half = lane >> 5, sub = lane & 31;
    // wave wv handles nodes start + wv*2 + half + 8*it ; lane holds float4 chunk `sub`
    float4 a = make_float4(0.f, 0.f, 0.f, 0.f);
    for (int i = start + wv * 2 + half; i < end; i += 8) {
        float4 v = ((const float4*)(H + (size_t)i * F))[sub];
        a.x += v.x; a.y += v.y; a.z += v.z; a.w += v.w;
    }
    a.x += __shfl_xor(a.x, 32, 64);
    a.y += __shfl_xor(a.y, 32, 64);
    a.z += __shfl_xor(a.z, 32, 64);
    a.w += __shfl_xor(a.w, 32, 64);
    if (half == 0) ((float4*)hs[wv])[sub] = a;
    __syncthreads();
    if (tid < F) {
        float inv = 1.0f / (float)((end - start) > 0 ? (end - start) : 1);
        hg[tid] = (hs[0][tid] + hs[1][tid] + hs[2][tid] + hs[3][tid]) * inv;
    }
    __syncthreads();
    if (tid < 64) {
        float acc = bf1[tid];
        #pragma unroll 4
        for (int f = 0; f < F; ++f) acc = fmaf(hg[f], Wf1[f * 64 + tid], acc);
        float v = fmaxf(acc, 0.f) * Wf2[tid];
        #pragma unroll
        for (int off = 32; off > 0; off >>= 1) v += __shfl_down(v, off, 64);
        if (tid == 0) out[g] = v + bf2[0];
    }
}

extern "C" void kernel_launch(void* const* d_in, const int* in_sizes, int n_in,
                              void* d_out, int out_size, void* d_ws, size_t ws_size,
                              hipStream_t stream) {
    const float* x    = (const float*)d_in[0];
    const int* eidx   = (const int*)d_in[1];
    const int* batch  = (const int*)d_in[2];
    const float* W1   = (const float*)d_in[3];
    const float* b1   = (const float*)d_in[4];
    const float* W2   = (const float*)d_in[5];
    const float* b2   = (const float*)d_in[6];
    const float* W3   = (const float*)d_in[7];
    const float* b3   = (const float*)d_in[8];
    const float* Wf1  = (const float*)d_in[9];
    const float* bf1  = (const float*)d_in[10];
    const float* Wf2  = (const float*)d_in[11];
    const float* bf2  = (const float*)d_in[12];
    float* out = (float*)d_out;

    const int* src = eidx;
    const int* dst = eidx + N_EDGES;

    char* p = (char*)d_ws;
    float* T    = (float*)p;   p += (size_t)N_NODES * F * sizeof(float);
    float* A    = (float*)p;   p += (size_t)N_NODES * F * sizeof(float);
    float* B    = (float*)p;   p += (size_t)N_NODES * F * sizeof(float);
    float* dinv = (float*)p;   p += (size_t)N_NODES * sizeof(float);
    int* cnt     = (int*)p;    p += (size_t)N_NODES * sizeof(int);
    int* row_ptr = (int*)p;    p += (size_t)(N_NODES + 1) * sizeof(int);
    int* blksums = (int*)p;    p += 256 * sizeof(int);
    int* esrc    = (int*)p;    p += (size_t)N_EDGES * sizeof(int);

    dim3 b256(256);
    int gNodes   = (N_NODES + 255) / 256;
    int gEdges   = (N_EDGES + 255) / 256;
    int gGemm    = (N_NODES + TM - 1) / TM;
    int gGather  = (N_NODES + 3) / 4;

    // ---- CSR build ----
    hipMemsetAsync(cnt, 0, (size_t)N_NODES * sizeof(int), stream);
    k_hist<<<gEdges, b256, 0, stream>>>(dst, cnt, N_EDGES);
    k_scan1<<<gNodes, b256, 0, stream>>>(cnt, row_ptr, blksums, dinv, N_NODES);
    k_scan2<<<1, b256, 0, stream>>>(blksums, gNodes);
    k_scan3<<<gNodes, b256, 0, stream>>>(row_ptr, blksums, N_NODES, N_EDGES);
    k_fill<<<gEdges, b256, 0, stream>>>(src, dst, row_ptr, cnt, esrc, N_EDGES);

    // ---- layer 1: x -> A ----
    k_gemm128<<<gGemm, b256, 0, stream>>>(x, W1, T, N_NODES);
    k_gather<<<gGather, b256, 0, stream>>>(row_ptr, esrc, dinv, T, b1, A, N_NODES);

    // ---- layer 2: A -> B ----
    k_gemm128<<<gGemm, b256, 0, stream>>>(A, W2, T, N_NODES);
    k_gather<<<gGather, b256, 0, stream>>>(row_ptr, esrc, dinv, T, b2, B, N_NODES);

    // ---- layer 3: B -> A ----
    k_gemm128<<<gGemm, b256, 0, stream>>>(B, W3, T, N_NODES);
    k_gather<<<gGather, b256, 0, stream>>>(row_ptr, esrc, dinv, T, b3, A, N_NODES);

    // ---- pool + FC ----
    k_pool_fc<<<N_GRAPHS, b256, 0, stream>>>(A, batch, Wf1, bf1, Wf2, bf2, out);
}